// Round 5
// baseline (386.934 us; speedup 1.0000x reference)
//
#include <hip/hip_runtime.h>
#include <hip/hip_fp16.h>
#include <hip/hip_cooperative_groups.h>
#include <math.h>

// Problem constants (fixed by the reference)
#define BN_NODES 16384     // B*N
#define DIM 128            // D
#define HID 256            // H
#define TK 4096            // distance-table knots (nearest-neighbor)
#define TRANGE 32.0f
#define TSTEP (TRANGE / (float)TK)   // 1/128
#define TINV  ((float)TK / TRANGE)   // 128
#define LN_EPS 1e-5f
#define EPB 4096           // edges per binning chunk
#define NBINS 1024         // 16-node bins
#define CAPB 768           // staging capacity per bin (mean 512, +11 sigma)

// role block ranges within the fused 512-block grid (512 threads each)
#define FB_TABLE_END 256   // 0..255  : Tb table, 16 knots/block (2 passes of 8)
#define FB_CONV_END  384   // 256..383: h -> xh/xq, 16384 floats/block
#define FB_W3T_END   416   // 384..415: w3t transpose (2 tiles/block)
#define FB_W4T_END   432   // 416..431: w4t transpose (2 tiles/block)
#define FB_BIN_START 432   // 432..511: edge binning, chunk-strided (80 blocks)

typedef _Float16 f16x8 __attribute__((ext_vector_type(8)));
typedef __attribute__((ext_vector_type(4))) float f32x4;
typedef __attribute__((ext_vector_type(2))) float floatx2;
typedef __attribute__((ext_vector_type(8))) unsigned short ushort8v;

__device__ __forceinline__ unsigned short f2h(float f) {
    _Float16 h = (_Float16)f;          // v_cvt_f16_f32, RNE
    return *(unsigned short*)&h;
}
__device__ __forceinline__ __half2 u2h2(unsigned int u) {
    union { unsigned int u; __half2 h; } c; c.u = u; return c.h;
}

// 8-dim accumulate for one edge: q = 8 fp8 dims of h_col, tv = 8 f16 table dims
__device__ __forceinline__ void acc8(uint2 q, uint4 tv, float* a) {
    floatx2 h01 = __builtin_amdgcn_cvt_pk_f32_fp8((int)q.x, false);
    floatx2 h23 = __builtin_amdgcn_cvt_pk_f32_fp8((int)q.x, true);
    floatx2 h45 = __builtin_amdgcn_cvt_pk_f32_fp8((int)q.y, false);
    floatx2 h67 = __builtin_amdgcn_cvt_pk_f32_fp8((int)q.y, true);
    __half2 t01 = u2h2(tv.x), t23 = u2h2(tv.y), t45 = u2h2(tv.z), t67 = u2h2(tv.w);
    a[0] = fmaf(h01[0], __low2float(t01),  a[0]);
    a[1] = fmaf(h01[1], __high2float(t01), a[1]);
    a[2] = fmaf(h23[0], __low2float(t23),  a[2]);
    a[3] = fmaf(h23[1], __high2float(t23), a[3]);
    a[4] = fmaf(h45[0], __low2float(t45),  a[4]);
    a[5] = fmaf(h45[1], __high2float(t45), a[5]);
    a[6] = fmaf(h67[0], __low2float(t67),  a[6]);
    a[7] = fmaf(h67[1], __high2float(t67), a[7]);
}

__device__ __forceinline__ void edge_one(const unsigned int* lrec, int idx, int dd,
        const unsigned char* __restrict__ xq,
        const unsigned short* __restrict__ Tb, float* a) {
    unsigned int r0 = lrec[idx];
    int c0 = (int)((r0 >> 12) & 0x3FFFu), k0 = (int)(r0 & 0xFFFu);
    uint2 q0 = *(const uint2*)&xq[c0 * DIM + dd];
    uint4 t0 = *(const uint4*)&Tb[k0 * DIM + dd];
    acc8(q0, t0, a);
}

// ---- LDS union for the fused kernel (30 KB max role) ----------------------
struct SMemTable { float a[8 * 256]; float part[3 * 8 * 128]; };         // 20 KB
struct SMemTp    { float s[2][32 * 33]; };                               // 8.4 KB
struct SMemBin   { int cnt[NBINS]; int pre[NBINS]; int gba[NBINS];
                   int sc[512]; unsigned int rec[EPB]; };                // 30 KB
struct SMemMega  { unsigned short aggh[16][136];
                   unsigned short a_lds[16][264];
                   unsigned int lrec[CAPB];
                   int cnt16[16]; int pref[17]; int cur[16];
                   float part_s[8][16]; float part_q[8][16];
                   float tot_mu[16]; float tot_rs[16]; };                // ~17.3 KB
union SMemU { SMemTable table; SMemTp tp; SMemBin bin; SMemMega mega; };

// ---------------------------------------------------------------------------
// Fused cooperative kernel, 512 blocks x 512 threads (2 bins/block in phase
// B). Needs only 2 blocks/CU co-residency vs a >=4 max (VGPR64/LDS30K/thr)
// -> 2x slack instead of r4's exact fit (suspected hipErrorCooperativeLaunch-
// TooLarge). Launch return code is checked; on failure the proven 3-op path
// runs instead.
__global__ __launch_bounds__(512, 8) void fused_kernel(
        const float* __restrict__ W1, const float* __restrict__ b1,
        const float* __restrict__ W2, const float* __restrict__ b2,
        const float* __restrict__ W3, const float* __restrict__ W4,
        const float* __restrict__ h, const int* __restrict__ ei,
        const float* __restrict__ x,
        unsigned short* __restrict__ Tb, unsigned short* __restrict__ w3t,
        unsigned short* __restrict__ w4t, unsigned short* __restrict__ xh,
        unsigned char* __restrict__ xq, int* __restrict__ bin_cursor,
        unsigned int* __restrict__ staging,
        const float* __restrict__ b3, const float* __restrict__ gamma,
        const float* __restrict__ beta, const float* __restrict__ b4,
        float* __restrict__ out, int nE) {
    __shared__ __align__(16) SMemU sm;
    cooperative_groups::grid_group grid = cooperative_groups::this_grid();
    int bid = blockIdx.x, t = threadIdx.x;

    // ---- phase A0: zero bin cursors (block 0; NBINS = 1024 = 2*512)
    if (bid == 0) { bin_cursor[t] = 0; bin_cursor[t + 512] = 0; }
    grid.sync();

    // ---- phase A: prep roles ------------------------------------------------
    if (bid < FB_TABLE_END) {
        // Tb[4096][128] fp16 table; 16 knots/block as two 8-knot passes
        float* a    = sm.table.a;     // [8][256]
        float* part = sm.table.part;  // [3][8][128]
        for (int pass = 0; pass < 2; ++pass) {
            int k0 = (bid * 2 + pass) * 8;
            if (t < 256) {
                float w1 = W1[t], bb = b1[t];
#pragma unroll
                for (int k = 0; k < 8; ++k) {
                    float dist = ((float)(k0 + k) + 0.5f) * TSTEP;   // cell center
                    float z = dist * w1 + bb;
                    a[k * 256 + t] = z / (1.0f + expf(-z));
                }
            }
            __syncthreads();
            int hg = t >> 7, d = t & 127;            // 4-way K split
            float acc[8] = {0.f,0.f,0.f,0.f,0.f,0.f,0.f,0.f};
            for (int hh = 0; hh < 64; ++hh) {
                int hidx = hg * 64 + hh;
                float w = W2[hidx * DIM + d];
#pragma unroll
                for (int k = 0; k < 8; ++k) acc[k] += a[k * 256 + hidx] * w;
            }
            if (hg) {
#pragma unroll
                for (int k = 0; k < 8; ++k) part[(hg - 1) * 1024 + k * 128 + d] = acc[k];
            }
            __syncthreads();
            if (hg == 0) {
                float bd = b2[d];
#pragma unroll
                for (int k = 0; k < 8; ++k)
                    Tb[(k0 + k) * DIM + d] = f2h(acc[k] + part[k * 128 + d]
                                                 + part[1024 + k * 128 + d]
                                                 + part[2048 + k * 128 + d] + bd);
            }
            __syncthreads();   // protect a/part before next pass
        }
    } else if (bid < FB_CONV_END) {
        // h -> xh fp16 AND xq fp8-e4m3; 16384 floats/block, 32/thread
        int base = (bid - FB_TABLE_END) * 16384 + t * 32;
#pragma unroll
        for (int rep = 0; rep < 2; ++rep) {
            int i0 = base + rep * 16;
            float4 v0 = *(const float4*)&h[i0];
            float4 v1 = *(const float4*)&h[i0 + 4];
            float4 v2 = *(const float4*)&h[i0 + 8];
            float4 v3 = *(const float4*)&h[i0 + 12];
            ushort8v o0, o1;
            o0[0] = f2h(v0.x); o0[1] = f2h(v0.y); o0[2] = f2h(v0.z); o0[3] = f2h(v0.w);
            o0[4] = f2h(v1.x); o0[5] = f2h(v1.y); o0[6] = f2h(v1.z); o0[7] = f2h(v1.w);
            o1[0] = f2h(v2.x); o1[1] = f2h(v2.y); o1[2] = f2h(v2.z); o1[3] = f2h(v2.w);
            o1[4] = f2h(v3.x); o1[5] = f2h(v3.y); o1[6] = f2h(v3.z); o1[7] = f2h(v3.w);
            *(ushort8v*)&xh[i0] = o0;
            *(ushort8v*)&xh[i0 + 8] = o1;
            unsigned int q0 = 0, q1 = 0, q2 = 0, q3 = 0;
            q0 = __builtin_amdgcn_cvt_pk_fp8_f32(v0.x, v0.y, q0, false);
            q0 = __builtin_amdgcn_cvt_pk_fp8_f32(v0.z, v0.w, q0, true);
            q1 = __builtin_amdgcn_cvt_pk_fp8_f32(v1.x, v1.y, q1, false);
            q1 = __builtin_amdgcn_cvt_pk_fp8_f32(v1.z, v1.w, q1, true);
            q2 = __builtin_amdgcn_cvt_pk_fp8_f32(v2.x, v2.y, q2, false);
            q2 = __builtin_amdgcn_cvt_pk_fp8_f32(v2.z, v2.w, q2, true);
            q3 = __builtin_amdgcn_cvt_pk_fp8_f32(v3.x, v3.y, q3, false);
            q3 = __builtin_amdgcn_cvt_pk_fp8_f32(v3.z, v3.w, q3, true);
            uint4 qq; qq.x = q0; qq.y = q1; qq.z = q2; qq.w = q3;
            *(uint4*)&xq[i0] = qq;
        }
    } else if (bid < FB_W3T_END) {
        // W3 -> w3t[n][k] fp16 transpose; two 32x32 tiles per block
        int half = t >> 8, tt = t & 255;
        int tid = (bid - FB_CONV_END) * 2 + half;    // 0..63
        float* s = sm.tp.s[half];                    // [32][33]
        int tr = tid >> 3, tc = tid & 7;
        int lr = tt >> 5, lc = tt & 31;
#pragma unroll
        for (int rep = 0; rep < 4; ++rep) {
            int k = tr * 32 + rep * 8 + lr, n = tc * 32 + lc;
            s[lc * 33 + rep * 8 + lr] = W3[k * 256 + n];
        }
        __syncthreads();
#pragma unroll
        for (int rep = 0; rep < 4; ++rep) {
            int n = tc * 32 + rep * 8 + lr, k = tr * 32 + lc;
            w3t[n * 256 + k] = f2h(s[(rep * 8 + lr) * 33 + lc]);
        }
    } else if (bid < FB_W4T_END) {
        // W4 -> w4t[n][k] fp16 transpose; two tiles per block
        int half = t >> 8, tt = t & 255;
        int tid = (bid - FB_W3T_END) * 2 + half;     // 0..31
        float* s = sm.tp.s[half];
        int tr = tid >> 2, tc = tid & 3;
        int lr = tt >> 5, lc = tt & 31;
#pragma unroll
        for (int rep = 0; rep < 4; ++rep) {
            int k = tr * 32 + rep * 8 + lr, n = tc * 32 + lc;
            s[lc * 33 + rep * 8 + lr] = W4[k * 128 + n];
        }
        __syncthreads();
#pragma unroll
        for (int rep = 0; rep < 4; ++rep) {
            int n = tc * 32 + rep * 8 + lr, k = tr * 32 + lc;
            w4t[n * 256 + k] = f2h(s[(rep * 8 + lr) * 33 + lc]);
        }
    } else {
        // edge binning: LDS counting-sort EPB-edge chunks into 1024 bins
        for (int chunk = bid - FB_BIN_START; (long)chunk * EPB < nE;
             chunk += (512 - FB_BIN_START)) {
            int e0 = chunk * EPB;
            int m = min(EPB, nE - e0);
#pragma unroll
            for (int j = 0; j < 2; ++j) sm.bin.cnt[j * 512 + t] = 0;
            __syncthreads();
            unsigned int code[8];
            int rk[8], bn[8];
#pragma unroll
            for (int j = 0; j < 8; ++j) {
                int idx = j * 512 + t;
                rk[j] = -1; bn[j] = 0; code[j] = 0;
                if (idx < m) {
                    int e = e0 + idx;
                    int r = ei[e], c = ei[nE + e];
                    code[j] = ((unsigned int)r << 14) | (unsigned int)c;  // 28b
                    bn[j] = r >> 4;
                    rk[j] = atomicAdd(&sm.bin.cnt[bn[j]], 1);
                }
            }
            __syncthreads();
            int c2[2], s2 = 0;
#pragma unroll
            for (int j = 0; j < 2; ++j) { c2[j] = sm.bin.cnt[t * 2 + j]; s2 += c2[j]; }
            sm.bin.sc[t] = s2;
            __syncthreads();
            for (int off = 1; off < 512; off <<= 1) {
                int v = (t >= off) ? sm.bin.sc[t - off] : 0;
                __syncthreads();
                sm.bin.sc[t] += v;
                __syncthreads();
            }
            int run = sm.bin.sc[t] - s2;
#pragma unroll
            for (int j = 0; j < 2; ++j) {
                int b = t * 2 + j;
                sm.bin.pre[b] = run; run += c2[j];
                sm.bin.gba[b] = atomicAdd(&bin_cursor[b], c2[j]);
            }
            __syncthreads();
#pragma unroll
            for (int j = 0; j < 8; ++j)
                if (rk[j] >= 0) sm.bin.rec[sm.bin.pre[bn[j]] + rk[j]] = code[j];
            __syncthreads();
            for (int i = t; i < m; i += 512) {
                unsigned int cd = sm.bin.rec[i];
                int b = (int)(cd >> 18);            // row >> 4
                int r = (int)(cd >> 14);
                int c = (int)(cd & 0x3FFFu);
                float dx = x[r * 3 + 0] - x[c * 3 + 0];
                float dy = x[r * 3 + 1] - x[c * 3 + 1];
                float dz = x[r * 3 + 2] - x[c * 3 + 2];
                float u = sqrtf(dx * dx + dy * dy + dz * dz) * TINV;
                int k = min((int)u, TK - 1);
                unsigned int o = ((unsigned int)(r & 15) << 26)
                               | ((unsigned int)c << 12) | (unsigned int)k;
                int off = sm.bin.gba[b] + (i - sm.bin.pre[b]);
                if (off < CAPB) staging[b * CAPB + off] = o;   // 11-sigma guard
            }
            __syncthreads();   // cnt reused next chunk
        }
    }

    __threadfence();
    grid.sync();

    // ---- phase B: mega, TWO bins per block (bid*2, bid*2+1) -----------------
    for (int halfb = 0; halfb < 2; ++halfb) {
        int bin = bid * 2 + halfb;
        int n0 = bin * 16;
        if (t < 16) sm.mega.cnt16[t] = 0;
        __syncthreads();
        int total = min(bin_cursor[bin], CAPB);
        long base = (long)bin * CAPB;

        unsigned int sr0 = 0, sr1 = 0;
        int have0 = (t < total), have1 = (t + 512 < total);
        if (have0) { sr0 = __builtin_nontemporal_load(&staging[base + t]);
                     atomicAdd(&sm.mega.cnt16[sr0 >> 26], 1); }
        if (have1) { sr1 = __builtin_nontemporal_load(&staging[base + t + 512]);
                     atomicAdd(&sm.mega.cnt16[sr1 >> 26], 1); }
        __syncthreads();
        if (t < 16) {
            int c = sm.mega.cnt16[t];
            int s = c;
#pragma unroll
            for (int off = 1; off < 16; off <<= 1) {
                int v = __shfl_up(s, off, 16);
                if (t >= off) s += v;
            }
            sm.mega.pref[t + 1] = s;
            sm.mega.cur[t] = s - c;
            if (t == 0) sm.mega.pref[0] = 0;
        }
        __syncthreads();
        if (have0) { int pos = atomicAdd(&sm.mega.cur[sr0 >> 26], 1); sm.mega.lrec[pos] = sr0; }
        if (have1) { int pos = atomicAdd(&sm.mega.cur[sr1 >> 26], 1); sm.mega.lrec[pos] = sr1; }
        __syncthreads();

        int wid = t >> 6, lane = t & 63;
        {
            int g = lane >> 4, l16 = lane & 15, dd = l16 * 8;
            int node = wid * 2 + (g >> 1);
            int sub = g & 1;
            int off = sm.mega.pref[node], len = sm.mega.pref[node + 1] - off;
            float a[8] = {0.f,0.f,0.f,0.f,0.f,0.f,0.f,0.f};
            int i = sub;
            for (; i + 2 < len; i += 4) {
                unsigned int r0 = sm.mega.lrec[off + i];
                unsigned int r1 = sm.mega.lrec[off + i + 2];
                int c0 = (int)((r0 >> 12) & 0x3FFFu), k0 = (int)(r0 & 0xFFFu);
                int c1 = (int)((r1 >> 12) & 0x3FFFu), k1 = (int)(r1 & 0xFFFu);
                uint2 q0 = *(const uint2*)&xq[c0 * DIM + dd];
                uint4 t0 = *(const uint4*)&Tb[k0 * DIM + dd];
                uint2 q1 = *(const uint2*)&xq[c1 * DIM + dd];
                uint4 t1 = *(const uint4*)&Tb[k1 * DIM + dd];
                acc8(q0, t0, a);
                acc8(q1, t1, a);
            }
            if (i < len)
                edge_one(sm.mega.lrec, off + i, dd, xq, Tb, a);
#pragma unroll
            for (int r = 0; r < 8; ++r) a[r] += __shfl_xor(a[r], 16, 64);
            if (sub == 0) {
                float inv = 1.0f / (float)max(len, 1);
                ushort8v o;
#pragma unroll
                for (int r = 0; r < 8; ++r) o[r] = f2h(a[r] * inv);
                *(ushort8v*)&sm.mega.aggh[node][dd] = o;
            }
        }
        __syncthreads();

        int wv = wid, q = lane >> 4, l15 = lane & 15;
        f32x4 acc[2];
        acc[0] = (f32x4){0.f, 0.f, 0.f, 0.f};
        acc[1] = (f32x4){0.f, 0.f, 0.f, 0.f};
        for (int kc = 0; kc < 8; ++kc) {
            f16x8 a;
            if (kc < 4) a = *(const f16x8*)&xh[(n0 + l15) * DIM + kc * 32 + q * 8];
            else        a = *(const f16x8*)&sm.mega.aggh[l15][(kc - 4) * 32 + q * 8];
#pragma unroll
            for (int nt = 0; nt < 2; ++nt) {
                f16x8 b = *(const f16x8*)&w3t[(wv * 32 + nt * 16 + l15) * 256 + kc * 32 + q * 8];
                acc[nt] = __builtin_amdgcn_mfma_f32_16x16x32_f16(a, b, acc[nt], 0, 0, 0);
            }
        }

        float b3v[2], gv[2], bvv[2];
#pragma unroll
        for (int nt = 0; nt < 2; ++nt) {
            int col = wv * 32 + nt * 16 + l15;
            b3v[nt] = b3[col]; gv[nt] = gamma[col]; bvv[nt] = beta[col];
        }
        {
            float s_[4], q_[4];
#pragma unroll
            for (int reg = 0; reg < 4; ++reg) {
                float su = 0.f, sq = 0.f;
#pragma unroll
                for (int nt = 0; nt < 2; ++nt) {
                    float v = acc[nt][reg] + b3v[nt];
                    acc[nt][reg] = v;
                    su += v; sq += v * v;
                }
                s_[reg] = su; q_[reg] = sq;
            }
#pragma unroll
            for (int off = 1; off < 16; off <<= 1) {
#pragma unroll
                for (int reg = 0; reg < 4; ++reg) {
                    s_[reg] += __shfl_xor(s_[reg], off, 64);
                    q_[reg] += __shfl_xor(q_[reg], off, 64);
                }
            }
            if (l15 == 0) {
#pragma unroll
                for (int reg = 0; reg < 4; ++reg) {
                    int r = q * 4 + reg;
                    sm.mega.part_s[wv][r] = s_[reg];
                    sm.mega.part_q[wv][r] = q_[reg];
                }
            }
        }
        __syncthreads();
        if (t < 16) {
            float st = 0.f, qt = 0.f;
#pragma unroll
            for (int w = 0; w < 8; ++w) { st += sm.mega.part_s[w][t]; qt += sm.mega.part_q[w][t]; }
            float mu = st * (1.0f / 256.0f);
            float var = qt * (1.0f / 256.0f) - mu * mu;
            sm.mega.tot_mu[t] = mu;
            sm.mega.tot_rs[t] = rsqrtf(var + LN_EPS);
        }
        __syncthreads();
#pragma unroll
        for (int reg = 0; reg < 4; ++reg) {
            int r = q * 4 + reg;
            float mu = sm.mega.tot_mu[r], rs = sm.mega.tot_rs[r];
#pragma unroll
            for (int nt = 0; nt < 2; ++nt) {
                float un = (acc[nt][reg] - mu) * rs * gv[nt] + bvv[nt];
                float act = un / (1.0f + expf(-un));
                sm.mega.a_lds[r][wv * 32 + nt * 16 + l15] = f2h(act);
            }
        }
        __syncthreads();

        f32x4 acc2 = (f32x4){0.f, 0.f, 0.f, 0.f};
        int col2 = wv * 16 + l15;
        for (int kc = 0; kc < 8; ++kc) {
            f16x8 a = *(const f16x8*)&sm.mega.a_lds[l15][kc * 32 + q * 8];
            f16x8 b = *(const f16x8*)&w4t[col2 * 256 + kc * 32 + q * 8];
            acc2 = __builtin_amdgcn_mfma_f32_16x16x32_f16(a, b, acc2, 0, 0, 0);
        }
        float b4v = b4[col2];
#pragma unroll
        for (int reg = 0; reg < 4; ++reg) {
            int node = n0 + q * 4 + reg;
            __builtin_nontemporal_store(acc2[reg] + b4v, &out[node * DIM + col2]);
        }
        __syncthreads();   // protect LDS before next bin
    }
}

// ===========================================================================
// FALLBACK PATH (r1 proven kernels, used only if cooperative enqueue fails)
// ===========================================================================
__global__ __launch_bounds__(256) void prep_kernel(
        const float* __restrict__ W1, const float* __restrict__ b1,
        const float* __restrict__ W2, const float* __restrict__ b2,
        const float* __restrict__ W3, const float* __restrict__ W4,
        const float* __restrict__ h, const int* __restrict__ ei,
        const float* __restrict__ x,
        unsigned short* __restrict__ Tb, unsigned short* __restrict__ w3t,
        unsigned short* __restrict__ w4t, unsigned short* __restrict__ xh,
        unsigned char* __restrict__ xq, int* __restrict__ bin_cursor,
        unsigned int* __restrict__ staging, int nE) {
    __shared__ float smem[8 * 256 + 8 * 128];
    int bid = blockIdx.x, t = threadIdx.x;
    if (bid < 512) {
        float* a    = smem;
        float* part = smem + 8 * 256;
        int k0 = bid * 8;
        float w1 = W1[t], bb = b1[t];
#pragma unroll
        for (int k = 0; k < 8; ++k) {
            float dist = ((float)(k0 + k) + 0.5f) * TSTEP;
            float z = dist * w1 + bb;
            a[k * 256 + t] = z / (1.0f + expf(-z));
        }
        __syncthreads();
        int hg = t >> 7, d = t & 127;
        float acc[8] = {0.f,0.f,0.f,0.f,0.f,0.f,0.f,0.f};
        for (int hh = 0; hh < 128; ++hh) {
            int hidx = hg * 128 + hh;
            float w = W2[hidx * DIM + d];
#pragma unroll
            for (int k = 0; k < 8; ++k) acc[k] += a[k * 256 + hidx] * w;
        }
        if (hg == 1) {
#pragma unroll
            for (int k = 0; k < 8; ++k) part[k * 128 + d] = acc[k];
        }
        __syncthreads();
        if (hg == 0) {
            float bd = b2[d];
#pragma unroll
            for (int k = 0; k < 8; ++k)
                Tb[(k0 + k) * DIM + d] = f2h(acc[k] + part[k * 128 + d] + bd);
        }
    } else if (bid < 576) {
        float* s = smem;
        int tid = bid - 512, tr = tid >> 3, tc = tid & 7;
        int lr = t >> 5, lc = t & 31;
#pragma unroll
        for (int rep = 0; rep < 4; ++rep) {
            int k = tr * 32 + rep * 8 + lr, n = tc * 32 + lc;
            s[lc * 33 + rep * 8 + lr] = W3[k * 256 + n];
        }
        __syncthreads();
#pragma unroll
        for (int rep = 0; rep < 4; ++rep) {
            int n = tc * 32 + rep * 8 + lr, k = tr * 32 + lc;
            w3t[n * 256 + k] = f2h(s[(rep * 8 + lr) * 33 + lc]);
        }
    } else if (bid < 608) {
        float* s = smem;
        int tid = bid - 576, tr = tid >> 2, tc = tid & 3;
        int lr = t >> 5, lc = t & 31;
#pragma unroll
        for (int rep = 0; rep < 4; ++rep) {
            int k = tr * 32 + rep * 8 + lr, n = tc * 32 + lc;
            s[lc * 33 + rep * 8 + lr] = W4[k * 128 + n];
        }
        __syncthreads();
#pragma unroll
        for (int rep = 0; rep < 4; ++rep) {
            int n = tc * 32 + rep * 8 + lr, k = tr * 32 + lc;
            w4t[n * 256 + k] = f2h(s[(rep * 8 + lr) * 33 + lc]);
        }
    } else if (bid < 1632) {
        int i0 = (bid - 608) * 2048 + t * 8;
        float4 v0 = *(const float4*)&h[i0];
        float4 v1 = *(const float4*)&h[i0 + 4];
        ushort8v o;
        o[0] = f2h(v0.x); o[1] = f2h(v0.y); o[2] = f2h(v0.z); o[3] = f2h(v0.w);
        o[4] = f2h(v1.x); o[5] = f2h(v1.y); o[6] = f2h(v1.z); o[7] = f2h(v1.w);
        *(ushort8v*)&xh[i0] = o;
        unsigned int q0 = 0, q1 = 0;
        q0 = __builtin_amdgcn_cvt_pk_fp8_f32(v0.x, v0.y, q0, false);
        q0 = __builtin_amdgcn_cvt_pk_fp8_f32(v0.z, v0.w, q0, true);
        q1 = __builtin_amdgcn_cvt_pk_fp8_f32(v1.x, v1.y, q1, false);
        q1 = __builtin_amdgcn_cvt_pk_fp8_f32(v1.z, v1.w, q1, true);
        uint2 qq; qq.x = q0; qq.y = q1;
        *(uint2*)&xq[i0] = qq;
    } else {
        __shared__ int cnt[NBINS];
        __shared__ int pre[NBINS];
        __shared__ int gba[NBINS];
        __shared__ int sc[256];
        __shared__ unsigned int rec[EPB];
        int e0 = (bid - 1632) * EPB;
        int m = min(EPB, nE - e0);
        if (m < 0) m = 0;
#pragma unroll
        for (int j = 0; j < 4; ++j) cnt[j * 256 + t] = 0;
        __syncthreads();
        unsigned int code[16];
        int rk[16], bn[16];
#pragma unroll
        for (int j = 0; j < 16; ++j) {
            int idx = j * 256 + t;
            rk[j] = -1; bn[j] = 0; code[j] = 0;
            if (idx < m) {
                int e = e0 + idx;
                int r = ei[e], c = ei[nE + e];
                code[j] = ((unsigned int)r << 14) | (unsigned int)c;
                bn[j] = r >> 4;
                rk[j] = atomicAdd(&cnt[bn[j]], 1);
            }
        }
        __syncthreads();
        int c4[4], s4 = 0;
#pragma unroll
        for (int j = 0; j < 4; ++j) { c4[j] = cnt[t * 4 + j]; s4 += c4[j]; }
        sc[t] = s4;
        __syncthreads();
        for (int off = 1; off < 256; off <<= 1) {
            int v = (t >= off) ? sc[t - off] : 0;
            __syncthreads();
            sc[t] += v;
            __syncthreads();
        }
        int run = sc[t] - s4;
#pragma unroll
        for (int j = 0; j < 4; ++j) {
            int b = t * 4 + j;
            pre[b] = run; run += c4[j];
            gba[b] = atomicAdd(&bin_cursor[b], c4[j]);
        }
        __syncthreads();
#pragma unroll
        for (int j = 0; j < 16; ++j)
            if (rk[j] >= 0) rec[pre[bn[j]] + rk[j]] = code[j];
        __syncthreads();
        for (int i = t; i < m; i += 256) {
            unsigned int cd = rec[i];
            int b = (int)(cd >> 18);
            int r = (int)(cd >> 14);
            int c = (int)(cd & 0x3FFFu);
            float dx = x[r * 3 + 0] - x[c * 3 + 0];
            float dy = x[r * 3 + 1] - x[c * 3 + 1];
            float dz = x[r * 3 + 2] - x[c * 3 + 2];
            float u = sqrtf(dx * dx + dy * dy + dz * dz) * TINV;
            int k = min((int)u, TK - 1);
            unsigned int o = ((unsigned int)(r & 15) << 26)
                           | ((unsigned int)c << 12) | (unsigned int)k;
            int off = gba[b] + (i - pre[b]);
            if (off < CAPB) staging[b * CAPB + off] = o;
        }
    }
}

__global__ __launch_bounds__(512, 8) void mega_kernel(
        const unsigned int* __restrict__ staging, const int* __restrict__ bin_cursor,
        const unsigned short* __restrict__ Tb, const unsigned char* __restrict__ xq,
        const unsigned short* __restrict__ xh, const unsigned short* __restrict__ w3t,
        const float* __restrict__ b3, const float* __restrict__ gamma,
        const float* __restrict__ beta, const unsigned short* __restrict__ w4t,
        const float* __restrict__ b4, float* __restrict__ out) {
    __shared__ unsigned int lrec[CAPB];
    __shared__ int cnt16[16];
    __shared__ int pref[17];
    __shared__ int cur[16];
    __shared__ __align__(16) unsigned short aggh[16][136];
    __shared__ __align__(16) unsigned short a_lds[16][264];
    __shared__ float part_s[8][16], part_q[8][16];
    __shared__ float tot_mu[16], tot_rs[16];

    int t = threadIdx.x;
    int bin = blockIdx.x;
    int n0 = bin * 16;
    if (t < 16) cnt16[t] = 0;
    __syncthreads();
    int total = min(bin_cursor[bin], CAPB);
    long base = (long)bin * CAPB;

    unsigned int sr0 = 0, sr1 = 0;
    int have0 = (t < total), have1 = (t + 512 < total);
    if (have0) { sr0 = __builtin_nontemporal_load(&staging[base + t]);
                 atomicAdd(&cnt16[sr0 >> 26], 1); }
    if (have1) { sr1 = __builtin_nontemporal_load(&staging[base + t + 512]);
                 atomicAdd(&cnt16[sr1 >> 26], 1); }
    __syncthreads();
    if (t < 16) {
        int c = cnt16[t];
        int s = c;
#pragma unroll
        for (int off = 1; off < 16; off <<= 1) {
            int v = __shfl_up(s, off, 16);
            if (t >= off) s += v;
        }
        pref[t + 1] = s;
        cur[t] = s - c;
        if (t == 0) pref[0] = 0;
    }
    __syncthreads();
    if (have0) { int pos = atomicAdd(&cur[sr0 >> 26], 1); lrec[pos] = sr0; }
    if (have1) { int pos = atomicAdd(&cur[sr1 >> 26], 1); lrec[pos] = sr1; }
    __syncthreads();

    int wid = t >> 6, lane = t & 63;
    {
        int g = lane >> 4, l16 = lane & 15, dd = l16 * 8;
        int node = wid * 2 + (g >> 1);
        int sub = g & 1;
        int off = pref[node], len = pref[node + 1] - off;
        float a[8] = {0.f,0.f,0.f,0.f,0.f,0.f,0.f,0.f};
        int i = sub;
        for (; i + 2 < len; i += 4) {
            unsigned int r0 = lrec[off + i];
            unsigned int r1 = lrec[off + i + 2];
            int c0 = (int)((r0 >> 12) & 0x3FFFu), k0 = (int)(r0 & 0xFFFu);
            int c1 = (int)((r1 >> 12) & 0x3FFFu), k1 = (int)(r1 & 0xFFFu);
            uint2 q0 = *(const uint2*)&xq[c0 * DIM + dd];
            uint4 t0 = *(const uint4*)&Tb[k0 * DIM + dd];
            uint2 q1 = *(const uint2*)&xq[c1 * DIM + dd];
            uint4 t1 = *(const uint4*)&Tb[k1 * DIM + dd];
            acc8(q0, t0, a);
            acc8(q1, t1, a);
        }
        if (i < len)
            edge_one(lrec, i + off, dd, xq, Tb, a);
#pragma unroll
        for (int r = 0; r < 8; ++r) a[r] += __shfl_xor(a[r], 16, 64);
        if (sub == 0) {
            float inv = 1.0f / (float)max(len, 1);
            ushort8v o;
#pragma unroll
            for (int r = 0; r < 8; ++r) o[r] = f2h(a[r] * inv);
            *(ushort8v*)&aggh[node][dd] = o;
        }
    }
    __syncthreads();

    int wv = wid, q = lane >> 4, l15 = lane & 15;
    f32x4 acc[2];
    acc[0] = (f32x4){0.f, 0.f, 0.f, 0.f};
    acc[1] = (f32x4){0.f, 0.f, 0.f, 0.f};
    for (int kc = 0; kc < 8; ++kc) {
        f16x8 a;
        if (kc < 4) a = *(const f16x8*)&xh[(n0 + l15) * DIM + kc * 32 + q * 8];
        else        a = *(const f16x8*)&aggh[l15][(kc - 4) * 32 + q * 8];
#pragma unroll
        for (int nt = 0; nt < 2; ++nt) {
            f16x8 b = *(const f16x8*)&w3t[(wv * 32 + nt * 16 + l15) * 256 + kc * 32 + q * 8];
            acc[nt] = __builtin_amdgcn_mfma_f32_16x16x32_f16(a, b, acc[nt], 0, 0, 0);
        }
    }
    float b3v[2], gv[2], bvv[2];
#pragma unroll
    for (int nt = 0; nt < 2; ++nt) {
        int col = wv * 32 + nt * 16 + l15;
        b3v[nt] = b3[col]; gv[nt] = gamma[col]; bvv[nt] = beta[col];
    }
    {
        float s_[4], q_[4];
#pragma unroll
        for (int reg = 0; reg < 4; ++reg) {
            float su = 0.f, sq = 0.f;
#pragma unroll
            for (int nt = 0; nt < 2; ++nt) {
                float v = acc[nt][reg] + b3v[nt];
                acc[nt][reg] = v;
                su += v; sq += v * v;
            }
            s_[reg] = su; q_[reg] = sq;
        }
#pragma unroll
        for (int off = 1; off < 16; off <<= 1) {
#pragma unroll
            for (int reg = 0; reg < 4; ++reg) {
                s_[reg] += __shfl_xor(s_[reg], off, 64);
                q_[reg] += __shfl_xor(q_[reg], off, 64);
            }
        }
        if (l15 == 0) {
#pragma unroll
            for (int reg = 0; reg < 4; ++reg) {
                int r = q * 4 + reg;
                part_s[wv][r] = s_[reg];
                part_q[wv][r] = q_[reg];
            }
        }
    }
    __syncthreads();
    if (t < 16) {
        float st = 0.f, qt = 0.f;
#pragma unroll
        for (int w = 0; w < 8; ++w) { st += part_s[w][t]; qt += part_q[w][t]; }
        float mu = st * (1.0f / 256.0f);
        float var = qt * (1.0f / 256.0f) - mu * mu;
        tot_mu[t] = mu;
        tot_rs[t] = rsqrtf(var + LN_EPS);
    }
    __syncthreads();
#pragma unroll
    for (int reg = 0; reg < 4; ++reg) {
        int r = q * 4 + reg;
        float mu = tot_mu[r], rs = tot_rs[r];
#pragma unroll
        for (int nt = 0; nt < 2; ++nt) {
            float un = (acc[nt][reg] - mu) * rs * gv[nt] + bvv[nt];
            float act = un / (1.0f + expf(-un));
            a_lds[r][wv * 32 + nt * 16 + l15] = f2h(act);
        }
    }
    __syncthreads();
    f32x4 acc2 = (f32x4){0.f, 0.f, 0.f, 0.f};
    int col2 = wv * 16 + l15;
    for (int kc = 0; kc < 8; ++kc) {
        f16x8 a = *(const f16x8*)&a_lds[l15][kc * 32 + q * 8];
        f16x8 b = *(const f16x8*)&w4t[col2 * 256 + kc * 32 + q * 8];
        acc2 = __builtin_amdgcn_mfma_f32_16x16x32_f16(a, b, acc2, 0, 0, 0);
    }
    float b4v = b4[col2];
#pragma unroll
    for (int reg = 0; reg < 4; ++reg) {
        int node = n0 + q * 4 + reg;
        __builtin_nontemporal_store(acc2[reg] + b4v, &out[node * DIM + col2]);
    }
}

// ---------------------------------------------------------------------------
extern "C" void kernel_launch(void* const* d_in, const int* in_sizes, int n_in,
                              void* d_out, int out_size, void* d_ws, size_t ws_size,
                              hipStream_t stream) {
    const float* x     = (const float*)d_in[0];
    const float* h     = (const float*)d_in[1];
    const int*   ei    = (const int*)d_in[2];
    const float* W1    = (const float*)d_in[4];
    const float* b1    = (const float*)d_in[5];
    const float* W2    = (const float*)d_in[6];
    const float* b2    = (const float*)d_in[7];
    const float* W3    = (const float*)d_in[8];
    const float* b3    = (const float*)d_in[9];
    const float* gamma = (const float*)d_in[10];
    const float* beta  = (const float*)d_in[11];
    const float* W4    = (const float*)d_in[12];
    const float* b4    = (const float*)d_in[13];
    float* out = (float*)d_out;
    int nE = in_sizes[2] / 2;

    char* ws = (char*)d_ws;
    unsigned short* Tb   = (unsigned short*)ws; ws += (size_t)TK * DIM * 2;       // 1 MB
    unsigned short* w3t  = (unsigned short*)ws; ws += (size_t)HID * HID * 2;      // 128 KB
    unsigned short* w4t  = (unsigned short*)ws; ws += (size_t)DIM * HID * 2;      // 64 KB
    unsigned short* xh   = (unsigned short*)ws; ws += (size_t)BN_NODES * DIM * 2; // 4 MB
    unsigned char*  xq   = (unsigned char*)ws;  ws += (size_t)BN_NODES * DIM;     // 2 MB
    int* bin_cursor = (int*)ws;                 ws += (size_t)NBINS * 4;          // 4 KB
    unsigned int* staging = (unsigned int*)ws;  ws += (size_t)NBINS * CAPB * 4;   // 3 MB

    void* args[] = {
        (void*)&W1, (void*)&b1, (void*)&W2, (void*)&b2, (void*)&W3, (void*)&W4,
        (void*)&h, (void*)&ei, (void*)&x,
        (void*)&Tb, (void*)&w3t, (void*)&w4t, (void*)&xh, (void*)&xq,
        (void*)&bin_cursor, (void*)&staging,
        (void*)&b3, (void*)&gamma, (void*)&beta, (void*)&b4,
        (void*)&out, (void*)&nE
    };
    hipError_t cerr = hipLaunchCooperativeKernel(
        reinterpret_cast<void*>(fused_kernel), dim3(512), dim3(512), args, 0, stream);
    if (cerr != hipSuccess) {
        // fallback: proven 3-op path (r1)
        int binBlocks = (nE + EPB - 1) / EPB;
        hipMemsetAsync(bin_cursor, 0, (size_t)NBINS * 4, stream);
        prep_kernel<<<1632 + binBlocks, 256, 0, stream>>>(W1, b1, W2, b2, W3, W4,
                                                          h, ei, x, Tb, w3t, w4t,
                                                          xh, xq, bin_cursor,
                                                          staging, nE);
        mega_kernel<<<NBINS, 512, 0, stream>>>(staging, bin_cursor, Tb, xq, xh,
                                               w3t, b3, gamma, beta, w4t, b4, out);
    }
}